// Round 1
// baseline (103.621 us; speedup 1.0000x reference)
//
#include <hip/hip_runtime.h>

#define T_TOK 32768
#define E_EXP 256
#define K_SEL 8
#define D_DEV 8
#define SLOTS (E_EXP / D_DEV)        // 32 experts per device
#define NBLK  1024
#define TOK_PER_BLK (T_TOK / NBLK)   // 32 tokens per block
#define TOK_PER_WAVE (TOK_PER_BLK / 4)  // 8 tokens per wave

// Streaming fused kernel (v2: coalesced row reads replace divergent gather).
//  Phase A (per block): expert setup (dev_of_expert + stable rank) via wave
//          ballots — overlapped with meta/mapping/row load latency.
//  Phase B (per wave, 8 tokens): full topk rows are loaded COALESCED
//          (8 x float4/lane = 1 KB/instr) into registers, staged into the
//          wave-private LDS tile, and the selected score topk[t][e] is
//          gathered from LDS (not HBM — kills the 64-way divergent VMEM
//          gather that was latency-bound). Tile is then zeroed in place and
//          the score scattered to its remapped position (gating by
//          construction). Device mask via 8 ballots on sdev[e].
//  Phase C: lane reads float4 tile[tt][lane*4] -> coalesced 1KB/token store
//          into out_remap[D][T][SLOTS]; lanes 0-31 write 4 mask rows (128 B).
// DS pipe is in-order per wave; asm memory clobbers stop compiler reordering
// across the cross-lane LDS dependencies (stage->gather, zero->scatter->read).
__global__ __launch_bounds__(256) void moe_fused_kernel(
    const float* __restrict__ topk, const int* __restrict__ mapping,
    const int* __restrict__ meta, float* __restrict__ out_remap,
    float* __restrict__ out_mask) {
  __shared__ float tile[4][TOK_PER_WAVE * E_EXP];  // 32 KB, wave-private rows
  __shared__ int sdev[E_EXP];
  __shared__ int spos[E_EXP];
  __shared__ int scnt[4 * D_DEV];

  const int tid  = threadIdx.x;
  const int w    = tid >> 6;
  const int lane = tid & 63;
  const int tbase = blockIdx.x * TOK_PER_BLK + w * TOK_PER_WAVE;

  // 1) issue all long-latency loads first: mapping (needed soonest), then
  //    meta, then the 8 coalesced row loads (needed after the setup phase).
  const int4 m0 = ((const int4*)mapping)[tid * 2];
  const int4 m1 = ((const int4*)mapping)[tid * 2 + 1];
  const int e = meta[(size_t)tbase * K_SEL + lane];  // lane = (tok,k) pair
  float4 rows[TOK_PER_WAVE];
#pragma unroll
  for (int i = 0; i < TOK_PER_WAVE; ++i)
    rows[i] = *(const float4*)&topk[(size_t)(tbase + i) * E_EXP + lane * 4];

  // 2) expert setup: thread tid = expert tid (overlaps row-load latency)
  {
    int vals[8] = {m0.x, m0.y, m0.z, m0.w, m1.x, m1.y, m1.z, m1.w};
    int best = vals[0], dev = 0;
#pragma unroll
    for (int d = 1; d < 8; ++d)
      if (vals[d] > best) { best = vals[d]; dev = d; }
    sdev[tid] = dev;

    unsigned long long myball = 0ull;
#pragma unroll
    for (int d = 0; d < 8; ++d) {
      unsigned long long b = __ballot(dev == d);
      if (d == dev) myball = b;
      if (lane == d) scnt[w * 8 + d] = __popcll(b);
    }
    const unsigned long long lt = (lane == 0) ? 0ull : (~0ull >> (64 - lane));
    const int lower = __popcll(myball & lt);
    __syncthreads();
    int base = 0;
    for (int d = 0; d < dev; ++d)
      base += scnt[0 * 8 + d] + scnt[1 * 8 + d] + scnt[2 * 8 + d] +
              scnt[3 * 8 + d];
    for (int w2 = 0; w2 < w; ++w2) base += scnt[w2 * 8 + dev];
    spos[tid] = base + lower;
    __syncthreads();
  }

  // 3) stage full rows into the wave-private tile (coalesced data arrived)
#pragma unroll
  for (int i = 0; i < TOK_PER_WAVE; ++i)
    *(float4*)&tile[w][i * E_EXP + lane * 4] = rows[i];
  asm volatile("" ::: "memory");  // stage-writes before cross-lane gather

  // 4) gather the selected score from LDS (was: divergent HBM gather)
  const float sc = tile[w][(lane >> 3) * E_EXP + e];
  const int pos = spos[e];   // remapped position 0..255
  const int dv  = sdev[e];   // device for the dispatch mask

  // 5) device-mask ballots: bit L of b_d <=> entry L (token L>>3) uses dev d.
  unsigned long long bsel = 0ull;
#pragma unroll
  for (int d = 0; d < D_DEV; ++d) {
    unsigned long long b = __ballot(dv == d);
    if ((lane & 7) == d) bsel = b;
  }
  // lanes 0..31: row r = lane>>3 (token pair 2r,2r+1 -> bits [16r,16r+16))
  const float fm =
      ((bsel >> (16 * (lane >> 3))) & 0xFFFFull) ? 1.0f : 0.0f;
  if (lane < 32)
    out_mask[(size_t)(tbase >> 1) * D_DEV + lane] = fm;  // 128 B contiguous

  // 6) zero the tile in place (gather read is already in the DS pipe ahead
  //    of these writes; pipe is in-order per wave), then scatter
  asm volatile("" ::: "memory");  // keep gather ds_read before zero-writes
  const float4 z4 = {0.f, 0.f, 0.f, 0.f};
#pragma unroll
  for (int i = 0; i < TOK_PER_WAVE; ++i)
    *(float4*)&tile[w][i * E_EXP + lane * 4] = z4;
  asm volatile("" ::: "memory");  // zero-writes before scatter
  tile[w][(lane >> 3) * E_EXP + pos] = sc;
  asm volatile("" ::: "memory");  // scatter before cross-lane readback

  // 7) coalesced write-out: lane owns positions [4*lane, 4*lane+4)
  const int dchunk = lane >> 3;          // (4*lane)>>5
  const int j      = (lane * 4) & 31;
  float* const obase =
      out_remap + (size_t)dchunk * T_TOK * SLOTS + j;
#pragma unroll
  for (int tt = 0; tt < TOK_PER_WAVE; ++tt) {
    const float4 v = *(const float4*)&tile[w][tt * E_EXP + lane * 4];
    *(float4*)(obase + (size_t)(tbase + tt) * SLOTS) = v;
  }
}

extern "C" void kernel_launch(void* const* d_in, const int* in_sizes, int n_in,
                              void* d_out, int out_size, void* d_ws, size_t ws_size,
                              hipStream_t stream) {
  const float* topk    = (const float*)d_in[0];
  const int*   mapping = (const int*)d_in[1];
  const int*   meta    = (const int*)d_in[2];

  float* out_remap = (float*)d_out;
  float* out_mask  = out_remap + (size_t)D_DEV * T_TOK * SLOTS;  // 8,388,608

  moe_fused_kernel<<<NBLK, 256, 0, stream>>>(topk, mapping, meta, out_remap,
                                             out_mask);
}

// Round 3
// 84.127 us; speedup vs baseline: 1.2317x; 1.2317x over previous
//
#include <hip/hip_runtime.h>

#define T_TOK 32768
#define E_EXP 256
#define K_SEL 8
#define D_DEV 8
#define SLOTS (E_EXP / D_DEV)        // 32 experts per device
#define NBLK  1024
#define TOK_PER_BLK (T_TOK / NBLK)   // 32 tokens per block
#define TOK_PER_WAVE (TOK_PER_BLK / 4)  // 8 tokens per wave

// Gather-based fused kernel (v3 = v1 + hoisted gather).
//  Phase A (per block): expert setup (dev_of_expert + stable rank) via wave
//          ballots — overlapped with the meta/mapping load latency.
//  Phase B (per wave, 8 tokens): lane = one (token, k) pair. The selected
//          score topk[t][e] is ISSUED BEFORE the setup phase (depends only on
//          the meta load, not on setup) so its ~900-cycle HBM latency is
//          hidden under the ballots + two __syncthreads instead of being
//          exposed after them. Scatter by remapped position into a per-wave
//          dense LDS tile [8][256] pre-filled with zeros (gating by
//          construction — no compares). Device mask via 8 ballots on sdev[e].
//  Phase C: lane reads float4 tile[tt][lane*4] -> coalesced 1KB/token store
//          into out_remap[D][T][SLOTS]; lanes 0-31 write 4 mask rows (128 B).
// Reads only ~420 B/token of topk instead of the full 1 KB row.
__global__ __launch_bounds__(256) void moe_fused_kernel(
    const float* __restrict__ topk, const int* __restrict__ mapping,
    const int* __restrict__ meta, float* __restrict__ out_remap,
    float* __restrict__ out_mask) {
  __shared__ float tile[4][TOK_PER_WAVE * E_EXP];  // 32 KB, wave-private rows
  __shared__ int sdev[E_EXP];
  __shared__ int spos[E_EXP];
  __shared__ int scnt[4 * D_DEV];

  const int tid  = threadIdx.x;
  const int w    = tid >> 6;
  const int lane = tid & 63;
  const int tbase = blockIdx.x * TOK_PER_BLK + w * TOK_PER_WAVE;
  const int tok   = tbase + (lane >> 3);   // this lane's gather token
  // 1) meta load first: 64 consecutive dwords per wave (coalesced 256 B)
  const int e = meta[(size_t)tbase * K_SEL + lane];

  // 2) mapping loads (2 x int4 per thread)
  const int4 m0 = ((const int4*)mapping)[tid * 2];
  const int4 m1 = ((const int4*)mapping)[tid * 2 + 1];

  // 3) HOISTED gather: depends only on e (waitcnt waits for meta, keeps the
  //    mapping loads in flight). The load stays outstanding across both
  //    __syncthreads of the setup phase; first use is the scatter below.
  const float sc = topk[(size_t)tok * E_EXP + e];

  // 4) zero the tile while all the above is in flight
  const float4 z4 = {0.f, 0.f, 0.f, 0.f};
#pragma unroll
  for (int i = 0; i < TOK_PER_WAVE; ++i)
    *(float4*)&tile[w][i * E_EXP + lane * 4] = z4;

  // 5) expert setup: thread tid = expert tid
  {
    int vals[8] = {m0.x, m0.y, m0.z, m0.w, m1.x, m1.y, m1.z, m1.w};
    int best = vals[0], dev = 0;
#pragma unroll
    for (int d = 1; d < 8; ++d)
      if (vals[d] > best) { best = vals[d]; dev = d; }
    sdev[tid] = dev;

    unsigned long long myball = 0ull;
#pragma unroll
    for (int d = 0; d < 8; ++d) {
      unsigned long long b = __ballot(dev == d);
      if (d == dev) myball = b;
      if (lane == d) scnt[w * 8 + d] = __popcll(b);
    }
    const unsigned long long lt = (lane == 0) ? 0ull : (~0ull >> (64 - lane));
    const int lower = __popcll(myball & lt);
    __syncthreads();
    int base = 0;
    for (int d = 0; d < dev; ++d)
      base += scnt[0 * 8 + d] + scnt[1 * 8 + d] + scnt[2 * 8 + d] +
              scnt[3 * 8 + d];
    for (int w2 = 0; w2 < w; ++w2) base += scnt[w2 * 8 + dev];
    spos[tid] = base + lower;
    __syncthreads();
  }

  // 6) remapped position + device for this (token, k) pair
  const int pos = spos[e];   // remapped position 0..255
  const int dv  = sdev[e];   // device for the dispatch mask

  // 7) device-mask ballots: bit L of b_d <=> entry L (token L>>3) uses dev d.
  //    Depends only on dv -> issues and stores before the gather returns.
  unsigned long long bsel = 0ull;
#pragma unroll
  for (int d = 0; d < D_DEV; ++d) {
    unsigned long long b = __ballot(dv == d);
    if ((lane & 7) == d) bsel = b;
  }
  // lanes 0..31: row r = lane>>3 (token pair 2r,2r+1 -> bits [16r,16r+16))
  const float fm =
      ((bsel >> (16 * (lane >> 3))) & 0xFFFFull) ? 1.0f : 0.0f;
  if (lane < 32)
    out_mask[(size_t)(tbase >> 1) * D_DEV + lane] = fm;  // 128 B contiguous

  // 8) scatter into the dense tile (wave-private; DS pipe is in-order per
  //    wave, so the zero-fill above is already ordered before this write).
  //    The compiler's s_waitcnt for sc lands HERE — latency already covered.
  tile[w][(lane >> 3) * E_EXP + pos] = sc;

  // 9) coalesced write-out: lane owns positions [4*lane, 4*lane+4)
  const int dchunk = lane >> 3;          // (4*lane)>>5
  const int j      = (lane * 4) & 31;
  float* const obase =
      out_remap + (size_t)dchunk * T_TOK * SLOTS + j;
#pragma unroll
  for (int tt = 0; tt < TOK_PER_WAVE; ++tt) {
    const float4 v = *(const float4*)&tile[w][tt * E_EXP + lane * 4];
    *(float4*)(obase + (size_t)(tbase + tt) * SLOTS) = v;
  }
}

extern "C" void kernel_launch(void* const* d_in, const int* in_sizes, int n_in,
                              void* d_out, int out_size, void* d_ws, size_t ws_size,
                              hipStream_t stream) {
  const float* topk    = (const float*)d_in[0];
  const int*   mapping = (const int*)d_in[1];
  const int*   meta    = (const int*)d_in[2];

  float* out_remap = (float*)d_out;
  float* out_mask  = out_remap + (size_t)D_DEV * T_TOK * SLOTS;  // 8,388,608

  moe_fused_kernel<<<NBLK, 256, 0, stream>>>(topk, mapping, meta, out_remap,
                                             out_mask);
}